// Round 7
// baseline (337.450 us; speedup 1.0000x reference)
//
#include <hip/hip_runtime.h>

// B=8, C=512, H=W=32, HW=1024, M=8192. scale = 1/sqrt(512).
// All GEMMs are LDS-free and barrier-free: each lane loads its MFMA A/B
// fragments directly from global memory (16 B contiguous per fragment),
// latency hidden by wave-level TLP (no __syncthreads in any K-loop).
// prep (x transpose->bf16, W pack->bf16)
// gemm_qk (bf16 MFMA -> fp8 q|k with bias)
// gemm_scores (fp8 MFMA, fused per-128-col-tile row max)
// softmax_xw ; gemm_out (bf16 MFMA, gating*xw + bias fused, transposed store)

typedef __attribute__((ext_vector_type(8))) short bf16x8;
typedef __attribute__((ext_vector_type(4))) float f32x4;
typedef __attribute__((ext_vector_type(2))) long long i64x2;

__device__ __forceinline__ unsigned short f2bf(float f) {
  unsigned u = __builtin_bit_cast(unsigned, f);
  u += 0x7FFFu + ((u >> 16) & 1u);
  return (unsigned short)(u >> 16);
}

// float -> OCP e4m3fn, RNE, saturate to 448.
__device__ __forceinline__ unsigned char f2e4m3(float x) {
  unsigned u = __builtin_bit_cast(unsigned, x);
  unsigned char s = (unsigned char)((u >> 24) & 0x80u);
  unsigned a = u & 0x7FFFFFFFu;
  if (a >= 0x43E00000u) return s | 0x7Eu;      // clamp to 448
  if (a < 0x3C800000u) {                        // below 2^-6: subnormal (quantum 2^-9)
    float q = __builtin_bit_cast(float, a) * 512.f;
    int m = (int)(q + 0.5f);
    return s | (unsigned char)m;
  }
  unsigned r = a + 0x7FFFFu + ((a >> 20) & 1u); // RNE at mantissa bit 20
  int e = (int)((r >> 23) & 0xFF) - 127;
  if (e > 8) return s | 0x7Eu;
  unsigned m3 = (r >> 20) & 0x7u;
  return s | (unsigned char)(((e + 7) << 3) | m3);
}

// ---------------------------------------------------------------------------
// prep: blocks [0,1024): transpose x [b][c][p] -> xt [b*1024+p][c] bf16
//       blocks [1024,1792): pack Wq|Wk|W6 -> wcat bf16 [1536][512]
__global__ __launch_bounds__(256) void prep(const float* __restrict__ x,
                                            const float* __restrict__ Wq,
                                            const float* __restrict__ Wk,
                                            const float* __restrict__ W6,
                                            short* __restrict__ xt,
                                            short* __restrict__ wcat) {
  const int bid = blockIdx.x, u = threadIdx.x;
  if (bid < 1024) {
    const int p0 = (bid & 15) * 64, c0 = ((bid >> 4) & 7) * 64, b = bid >> 7;
    __shared__ float t[64][65];
    {
      const int p4 = u & 15, cr = u >> 4;
      for (int cc = 0; cc < 4; ++cc) {
        const int c = cc * 16 + cr;
        const float4 v = *(const float4*)&x[((size_t)(b * 512 + c0 + c)) * 1024 + p0 + p4 * 4];
        t[p4 * 4 + 0][c] = v.x; t[p4 * 4 + 1][c] = v.y;
        t[p4 * 4 + 2][c] = v.z; t[p4 * 4 + 3][c] = v.w;
      }
    }
    __syncthreads();
    {
      const int c4 = u & 15, pr = u >> 4;
      for (int pp = 0; pp < 4; ++pp) {
        const int p = pp * 16 + pr;
        ushort4 o;
        o.x = f2bf(t[p][c4 * 4 + 0]); o.y = f2bf(t[p][c4 * 4 + 1]);
        o.z = f2bf(t[p][c4 * 4 + 2]); o.w = f2bf(t[p][c4 * 4 + 3]);
        *(ushort4*)&xt[((size_t)(b * 1024 + p0 + p)) * 512 + c0 + c4 * 4] = o;
      }
    }
  } else {
    const int i = (bid - 1024) * 256 + u;
    const int idx = i * 4;
    const float* src = (idx < 262144) ? Wq : (idx < 524288) ? Wk : W6;
    const float4 v = *(const float4*)&src[idx & 262143];
    ushort4 o;
    o.x = f2bf(v.x); o.y = f2bf(v.y); o.z = f2bf(v.z); o.w = f2bf(v.w);
    *(ushort4*)&wcat[idx] = o;
  }
}

// ---------------------------------------------------------------------------
// gemm_qk: [8192][1024] = xt @ wcat[0:1024]^T + bias -> fp8 qk8
// LDS-free / barrier-free. Block 64 rows x 128 cols, grid (128, 8).
// Wave w owns rows [m0 + w*16, +16) x all 128 cols: acc[8].
// A frag: 16 B at xt[(row16 + lane&15)*512 + kt*32 + quad*8]
// B frag: 16 B at wcat[(n0 + j*16 + lane&15)*512 + kt*32 + quad*8]
__global__ __launch_bounds__(256) void gemm_qk(const short* __restrict__ xt,
                                               const short* __restrict__ wcat,
                                               const float* __restrict__ bq,
                                               const float* __restrict__ bk,
                                               unsigned char* __restrict__ qk8) {
  const int tid = threadIdx.x, w = tid >> 6, lane = tid & 63;
  const int quad = lane >> 4, lcol = lane & 15;
  const int m0 = blockIdx.x * 64, n0 = blockIdx.y * 128;

  f32x4 acc[8];
#pragma unroll
  for (int j = 0; j < 8; ++j)
#pragma unroll
    for (int r = 0; r < 4; ++r) acc[j][r] = 0.f;

  const short* Abase = xt + (size_t)(m0 + w * 16 + lcol) * 512 + quad * 8;
  const short* Bbase = wcat + (size_t)(n0 + lcol) * 512 + quad * 8;

#pragma unroll
  for (int kt = 0; kt < 16; ++kt) {
    const int kb = kt * 32;
    const bf16x8 af = *(const bf16x8*)(Abase + kb);
#pragma unroll
    for (int j = 0; j < 8; ++j) {
      const bf16x8 bf = *(const bf16x8*)(Bbase + (size_t)(j * 16) * 512 + kb);
      acc[j] = __builtin_amdgcn_mfma_f32_16x16x32_bf16(af, bf, acc[j], 0, 0, 0);
    }
  }

  const float* bias = (blockIdx.y >= 4) ? bk : bq;
  const int row = m0 + w * 16 + quad * 4;
#pragma unroll
  for (int j = 0; j < 8; ++j) {
    const int col = n0 + j * 16 + lcol;
    const float bv = bias[col & 511];
#pragma unroll
    for (int r = 0; r < 4; ++r)
      qk8[(size_t)(row + r) * 1024 + col] = f2e4m3(acc[j][r] + bv);
  }
}

// ---------------------------------------------------------------------------
// gemm_scores: q @ k^T (fp8 MFMA), LDS-free / barrier-free.
// Block 128x128, grid (64,64); wave w owns rows [m0+w*32,+32): acc[2][8].
// Per 64-byte k-chunk: lane's 16 B at chunk*64 + quad*16; low 8 B -> mfma .x,
// high 8 B -> mfma .y (identical A/B k-permutation => exact dot product).
// Fused per-row max over this 128-col tile -> wsmx[coltile][m].
__global__ __launch_bounds__(256) void gemm_scores(const unsigned char* __restrict__ qk8,
                                                   float* __restrict__ wsmx) {
  const int tid = threadIdx.x, w = tid >> 6, lane = tid & 63;
  const int quad = lane >> 4, lcol = lane & 15;
  const int m0 = blockIdx.x * 128, n0 = blockIdx.y * 128;

  f32x4 acc[2][8];
#pragma unroll
  for (int rg = 0; rg < 2; ++rg)
#pragma unroll
    for (int j = 0; j < 8; ++j)
#pragma unroll
      for (int r = 0; r < 4; ++r) acc[rg][j][r] = 0.f;

  const unsigned char* Abase = qk8 + (size_t)(m0 + w * 32 + lcol) * 1024 + quad * 16;
  const unsigned char* Bbase = qk8 + (size_t)(n0 + lcol) * 1024 + 512 + quad * 16;

#pragma unroll
  for (int c = 0; c < 8; ++c) {
    const int kb = c * 64;
    i64x2 af[2];
#pragma unroll
    for (int rg = 0; rg < 2; ++rg)
      af[rg] = *(const i64x2*)(Abase + (size_t)rg * 16384 + kb);
#pragma unroll
    for (int j = 0; j < 8; ++j) {
      const i64x2 bf = *(const i64x2*)(Bbase + (size_t)(j * 16) * 1024 + kb);
#pragma unroll
      for (int rg = 0; rg < 2; ++rg) {
        acc[rg][j] = __builtin_amdgcn_mfma_f32_16x16x32_fp8_fp8(
            af[rg].x, bf.x, acc[rg][j], 0, 0, 0);
        acc[rg][j] = __builtin_amdgcn_mfma_f32_16x16x32_fp8_fp8(
            af[rg].y, bf.y, acc[rg][j], 0, 0, 0);
      }
    }
  }

  // per-row max over all 128 cols: wave-local (rows are wave-exclusive)
#pragma unroll
  for (int rg = 0; rg < 2; ++rg) {
#pragma unroll
    for (int r = 0; r < 4; ++r) {
      float v = acc[rg][0][r];
#pragma unroll
      for (int j = 1; j < 8; ++j) v = fmaxf(v, acc[rg][j][r]);
#pragma unroll
      for (int off = 1; off < 16; off <<= 1) v = fmaxf(v, __shfl_xor(v, off));
      if (lcol == 0)
        wsmx[(size_t)blockIdx.y * 8192 + m0 + w * 32 + rg * 16 + quad * 4 + r] = v;
    }
  }
}

// ---------------------------------------------------------------------------
// softmax_xw: logit[m] = scale * mean_img( max over img's 8 col-tiles ); softmax per image
__global__ __launch_bounds__(1024) void softmax_xw(const float* __restrict__ wsmx,
                                                   float* __restrict__ xw) {
  const int b = blockIdx.x, p = threadIdx.x;
  const int m = b * 1024 + p;
  float s = 0.f;
#pragma unroll
  for (int img = 0; img < 8; ++img) {
    float mx = -1e30f;
#pragma unroll
    for (int t = 0; t < 8; ++t) mx = fmaxf(mx, wsmx[(size_t)(img * 8 + t) * 8192 + m]);
    s += mx;
  }
  const float logit = s * 0.005524271728019903f;  // (1/8) * (1/sqrt(512))
  __shared__ float red[16];
  float v = logit;
#pragma unroll
  for (int off = 32; off >= 1; off >>= 1) v = fmaxf(v, __shfl_xor(v, off));
  if ((p & 63) == 0) red[p >> 6] = v;
  __syncthreads();
  float bmax = red[0];
#pragma unroll
  for (int t = 1; t < 16; ++t) bmax = fmaxf(bmax, red[t]);
  const float e = expf(logit - bmax);
  float sv = e;
#pragma unroll
  for (int off = 32; off >= 1; off >>= 1) sv += __shfl_xor(sv, off);
  __syncthreads();
  if ((p & 63) == 0) red[p >> 6] = sv;
  __syncthreads();
  float bsum = 0.f;
#pragma unroll
  for (int t = 0; t < 16; ++t) bsum += red[t];
  xw[m] = e / bsum;
}

// ---------------------------------------------------------------------------
// gemm_out: out[b][co][p] = (xt @ W6^T)[m][co] * xw[m] + b6[co], m = b*1024+p.
// LDS-free / barrier-free. Block 64 rows x 64 cols, grid (128, 8).
// Wave w owns rows [m0 + w*16, +16) x all 64 cols: acc[4].
__global__ __launch_bounds__(256) void gemm_out(const short* __restrict__ xt,
                                                const short* __restrict__ wcat,
                                                const float* __restrict__ xw,
                                                const float* __restrict__ b6,
                                                float* __restrict__ out) {
  const int tid = threadIdx.x, w = tid >> 6, lane = tid & 63;
  const int quad = lane >> 4, lcol = lane & 15;
  const int m0 = blockIdx.x * 64, n0 = blockIdx.y * 64;

  f32x4 acc[4];
#pragma unroll
  for (int j = 0; j < 4; ++j)
#pragma unroll
    for (int r = 0; r < 4; ++r) acc[j][r] = 0.f;

  const short* Abase = xt + (size_t)(m0 + w * 16 + lcol) * 512 + quad * 8;
  const short* Bbase = wcat + (size_t)(1024 + n0 + lcol) * 512 + quad * 8;

#pragma unroll
  for (int kt = 0; kt < 16; ++kt) {
    const int kb = kt * 32;
    const bf16x8 af = *(const bf16x8*)(Abase + kb);
#pragma unroll
    for (int j = 0; j < 4; ++j) {
      const bf16x8 bf = *(const bf16x8*)(Bbase + (size_t)(j * 16) * 512 + kb);
      acc[j] = __builtin_amdgcn_mfma_f32_16x16x32_bf16(af, bf, acc[j], 0, 0, 0);
    }
  }

  const int mbase = m0 + w * 16 + quad * 4;
  const int b = mbase >> 10, p = mbase & 1023;
  const float4 wv = *(const float4*)&xw[mbase];
#pragma unroll
  for (int j = 0; j < 4; ++j) {
    const int col = n0 + j * 16 + lcol;
    const float bias = b6[col];
    float4 o;
    o.x = acc[j][0] * wv.x + bias;
    o.y = acc[j][1] * wv.y + bias;
    o.z = acc[j][2] * wv.z + bias;
    o.w = acc[j][3] * wv.w + bias;
    *(float4*)&out[((size_t)(b * 512 + col)) * 1024 + p] = o;
  }
}

// ---------------------------------------------------------------------------
extern "C" void kernel_launch(void* const* d_in, const int* in_sizes, int n_in,
                              void* d_out, int out_size, void* d_ws, size_t ws_size,
                              hipStream_t stream) {
  const float* x  = (const float*)d_in[0];
  const float* Wq = (const float*)d_in[1];
  const float* bq = (const float*)d_in[2];
  const float* Wk = (const float*)d_in[3];
  const float* bk = (const float*)d_in[4];
  const float* W6 = (const float*)d_in[5];
  const float* b6 = (const float*)d_in[6];
  float* out = (float*)d_out;

  char* ws = (char*)d_ws;
  short* xt          = (short*)(ws + 0);               //  8 MB  bf16 [8192][512]
  short* wcat        = (short*)(ws + 8388608);         //  1.5MB bf16 [1536][512]
  unsigned char* qk8 = (unsigned char*)(ws + 10485760);//  8 MB  fp8  [8192][1024]
  float* wsmx        = (float*)(ws + 18874368);        //  2 MB  fp32 [64][8192]
  float* xw          = (float*)(ws + 20971520);        // 32 KB  fp32 [8192]

  prep<<<1792, 256, 0, stream>>>(x, Wq, Wk, W6, xt, wcat);
  gemm_qk<<<dim3(128, 8), 256, 0, stream>>>(xt, wcat, bq, bk, qk8);
  gemm_scores<<<dim3(64, 64), 256, 0, stream>>>(qk8, wsmx);
  softmax_xw<<<8, 1024, 0, stream>>>(wsmx, xw);
  gemm_out<<<dim3(128, 8), 256, 0, stream>>>(xt, wcat, xw, b6, out);
}

// Round 8
// 191.729 us; speedup vs baseline: 1.7600x; 1.7600x over previous
//
#include <hip/hip_runtime.h>

// B=8, C=512, H=W=32, HW=1024, M=8192. scale = 1/sqrt(512).
// prep (x transpose->bf16, W pack->bf16)  [1 launch]
// gemm_qkz (bf16 MFMA, BK=32 frag-ordered; q|k -> fp8 qk8 (+bias), z -> bf16)
// gemm_scores (fp8 MFMA, R5 hybrid: A per-lane global, B staged LDS, 4 barriers)
// softmax_xw ; epilogue_out (out = z*xw + b6, LDS transpose, z in bf16)

typedef __attribute__((ext_vector_type(8))) short bf16x8;
typedef __attribute__((ext_vector_type(4))) float f32x4;
typedef __attribute__((ext_vector_type(2))) long long i64x2;

__device__ __forceinline__ unsigned short f2bf(float f) {
  unsigned u = __builtin_bit_cast(unsigned, f);
  u += 0x7FFFu + ((u >> 16) & 1u);
  return (unsigned short)(u >> 16);
}

__device__ __forceinline__ float bf2f(unsigned short b) {
  return __builtin_bit_cast(float, (unsigned)b << 16);
}

// float -> OCP e4m3fn, RNE, saturate to 448.
__device__ __forceinline__ unsigned char f2e4m3(float x) {
  unsigned u = __builtin_bit_cast(unsigned, x);
  unsigned char s = (unsigned char)((u >> 24) & 0x80u);
  unsigned a = u & 0x7FFFFFFFu;
  if (a >= 0x43E00000u) return s | 0x7Eu;      // clamp to 448
  if (a < 0x3C800000u) {                        // below 2^-6: subnormal (quantum 2^-9)
    float q = __builtin_bit_cast(float, a) * 512.f;
    int m = (int)(q + 0.5f);
    return s | (unsigned char)m;
  }
  unsigned r = a + 0x7FFFFu + ((a >> 20) & 1u); // RNE at mantissa bit 20
  int e = (int)((r >> 23) & 0xFF) - 127;
  if (e > 8) return s | 0x7Eu;
  unsigned m3 = (r >> 20) & 0x7u;
  return s | (unsigned char)(((e + 7) << 3) | m3);
}

__device__ __forceinline__ void gload_lds16(const void* g, void* l) {
  __builtin_amdgcn_global_load_lds(
      (const __attribute__((address_space(1))) unsigned int*)g,
      (__attribute__((address_space(3))) unsigned int*)l, 16, 0, 0);
}

// ---------------------------------------------------------------------------
// prep: blocks [0,1024): transpose x [b][c][p] -> xt [b*1024+p][c] bf16
//       blocks [1024,1792): pack Wq|Wk|W6 -> wcat bf16 [1536][512]
__global__ __launch_bounds__(256) void prep(const float* __restrict__ x,
                                            const float* __restrict__ Wq,
                                            const float* __restrict__ Wk,
                                            const float* __restrict__ W6,
                                            short* __restrict__ xt,
                                            short* __restrict__ wcat) {
  const int bid = blockIdx.x, u = threadIdx.x;
  if (bid < 1024) {
    const int p0 = (bid & 15) * 64, c0 = ((bid >> 4) & 7) * 64, b = bid >> 7;
    __shared__ float t[64][65];
    {
      const int p4 = u & 15, cr = u >> 4;
      for (int cc = 0; cc < 4; ++cc) {
        const int c = cc * 16 + cr;
        const float4 v = *(const float4*)&x[((size_t)(b * 512 + c0 + c)) * 1024 + p0 + p4 * 4];
        t[p4 * 4 + 0][c] = v.x; t[p4 * 4 + 1][c] = v.y;
        t[p4 * 4 + 2][c] = v.z; t[p4 * 4 + 3][c] = v.w;
      }
    }
    __syncthreads();
    {
      const int c4 = u & 15, pr = u >> 4;
      for (int pp = 0; pp < 4; ++pp) {
        const int p = pp * 16 + pr;
        ushort4 o;
        o.x = f2bf(t[p][c4 * 4 + 0]); o.y = f2bf(t[p][c4 * 4 + 1]);
        o.z = f2bf(t[p][c4 * 4 + 2]); o.w = f2bf(t[p][c4 * 4 + 3]);
        *(ushort4*)&xt[((size_t)(b * 1024 + p0 + p)) * 512 + c0 + c4 * 4] = o;
      }
    }
  } else {
    const int i = (bid - 1024) * 256 + u;
    const int idx = i * 4;
    const float* src = (idx < 262144) ? Wq : (idx < 524288) ? Wk : W6;
    const float4 v = *(const float4*)&src[idx & 262143];
    ushort4 o;
    o.x = f2bf(v.x); o.y = f2bf(v.y); o.z = f2bf(v.z); o.w = f2bf(v.w);
    *(ushort4*)&wcat[idx] = o;
  }
}

// ---------------------------------------------------------------------------
// gemm_qkz: C[8192][1536] = xt @ wcat^T. Cols 0..1023 -> qk8 fp8 (+bias);
// cols 1024..1535 -> z bf16 (no bias; b6 applied in epilogue).
// 128x128 tile, BK=32, frag-ordered conflict-free LDS (R2 layout). grid (64,12).
__global__ __launch_bounds__(256) void gemm_qkz(const short* __restrict__ xt,
                                                const short* __restrict__ wcat,
                                                const float* __restrict__ bq,
                                                const float* __restrict__ bk,
                                                unsigned char* __restrict__ qk8,
                                                short* __restrict__ z) {
  __shared__ short lds_a[128 * 32];  // 8 KB
  __shared__ short lds_b[128 * 32];
  const int tid = threadIdx.x, w = tid >> 6, lane = tid & 63;
  const int wr = w >> 1, wc = w & 1;
  const int quad = lane >> 4, lcol = lane & 15;
  const int srow = lane & 15, skq = lane >> 4;
  const int m0 = blockIdx.x * 128, n0 = blockIdx.y * 128;

  f32x4 acc[4][4];
#pragma unroll
  for (int i = 0; i < 4; ++i)
#pragma unroll
    for (int j = 0; j < 4; ++j)
#pragma unroll
      for (int r = 0; r < 4; ++r) acc[i][j][r] = 0.f;

  const short* Abase = xt + (size_t)(m0 + srow) * 512 + skq * 8;
  const short* Bbase = wcat + (size_t)(n0 + srow) * 512 + skq * 8;

  for (int kt = 0; kt < 16; ++kt) {
    const int kb = kt * 32;
    __syncthreads();
    gload_lds16(Abase + (size_t)(w * 16) * 512 + kb,       lds_a + w * 512);
    gload_lds16(Abase + (size_t)((4 + w) * 16) * 512 + kb, lds_a + (4 + w) * 512);
    gload_lds16(Bbase + (size_t)(w * 16) * 512 + kb,       lds_b + w * 512);
    gload_lds16(Bbase + (size_t)((4 + w) * 16) * 512 + kb, lds_b + (4 + w) * 512);
    __syncthreads();
    bf16x8 af[4], bf[4];
#pragma unroll
    for (int i = 0; i < 4; ++i) af[i] = *(const bf16x8*)&lds_a[(wr * 4 + i) * 512 + lane * 8];
#pragma unroll
    for (int j = 0; j < 4; ++j) bf[j] = *(const bf16x8*)&lds_b[(wc * 4 + j) * 512 + lane * 8];
#pragma unroll
    for (int i = 0; i < 4; ++i)
#pragma unroll
      for (int j = 0; j < 4; ++j)
        acc[i][j] = __builtin_amdgcn_mfma_f32_16x16x32_bf16(af[i], bf[j], acc[i][j], 0, 0, 0);
  }

  const int region = (int)blockIdx.y >> 2;  // 0=q, 1=k, 2=z (uniform per block)
  if (region < 2) {
    const float* bias = region ? bk : bq;
#pragma unroll
    for (int i = 0; i < 4; ++i)
#pragma unroll
      for (int j = 0; j < 4; ++j) {
        const int row = m0 + wr * 64 + i * 16 + quad * 4;
        const int col = n0 + wc * 64 + j * 16 + lcol;
        const float bv = bias[col & 511];
#pragma unroll
        for (int r = 0; r < 4; ++r)
          qk8[(size_t)(row + r) * 1024 + col] = f2e4m3(acc[i][j][r] + bv);
      }
  } else {
#pragma unroll
    for (int i = 0; i < 4; ++i)
#pragma unroll
      for (int j = 0; j < 4; ++j) {
        const int row = m0 + wr * 64 + i * 16 + quad * 4;
        const int col = n0 - 1024 + wc * 64 + j * 16 + lcol;
#pragma unroll
        for (int r = 0; r < 4; ++r)
          z[(size_t)(row + r) * 512 + col] = (short)f2bf(acc[i][j][r]);
      }
  }
}

// ---------------------------------------------------------------------------
// gemm_scores: q @ k^T (fp8 MFMA), R5 hybrid structure [71.6 us measured].
// Block tile 128x128; wave w owns rows [m0+w*32, +32) x all 128 cols: acc[2][8].
// A streamed per-lane straight from global; B staged in LDS in 2 half-K
// (256 B) stages, frag-ordered. 4 __syncthreads per block.
__global__ __launch_bounds__(256) void gemm_scores(const unsigned char* __restrict__ qk8,
                                                   float* __restrict__ wsmx) {
  __shared__ unsigned char lds_b[32768];
  const int tid = threadIdx.x, w = tid >> 6, lane = tid & 63;
  const int quad = lane >> 4, lcol = lane & 15;
  const int srow = lane & 15, skb = (lane >> 4) * 16;
  const int m0 = blockIdx.x * 128, n0 = blockIdx.y * 128;

  f32x4 acc[2][8];
#pragma unroll
  for (int rg = 0; rg < 2; ++rg)
#pragma unroll
    for (int j = 0; j < 8; ++j)
#pragma unroll
      for (int r = 0; r < 4; ++r) acc[rg][j][r] = 0.f;

  const unsigned char* Abase = qk8 + (size_t)(m0 + w * 32 + srow) * 1024 + skb;
  const unsigned char* Bbase = qk8 + (size_t)(n0 + srow) * 1024 + 512 + skb;

#pragma unroll
  for (int kh = 0; kh < 2; ++kh) {
    __syncthreads();  // previous half fully consumed before overwrite
#pragma unroll
    for (int jj = 0; jj < 2; ++jj) {
      const int j = w * 2 + jj;
#pragma unroll
      for (int kb = 0; kb < 4; ++kb)
        gload_lds16(Bbase + (size_t)(j * 16) * 1024 + kh * 256 + kb * 64,
                    lds_b + j * 4096 + kb * 1024);
    }
    // prefetch this half's A (8 x 16B) while glds are in flight
    i64x2 af[2][4];
#pragma unroll
    for (int rg = 0; rg < 2; ++rg)
#pragma unroll
      for (int kb = 0; kb < 4; ++kb)
        af[rg][kb] = *(const i64x2*)(Abase + (size_t)rg * 16384 + kh * 256 + kb * 64);
    __syncthreads();  // B half ready
#pragma unroll
    for (int kb = 0; kb < 4; ++kb) {
#pragma unroll
      for (int j = 0; j < 8; ++j) {
        const i64x2 bf = *(const i64x2*)&lds_b[j * 4096 + kb * 1024 + lane * 16];
#pragma unroll
        for (int rg = 0; rg < 2; ++rg) {
          acc[rg][j] = __builtin_amdgcn_mfma_f32_16x16x32_fp8_fp8(
              af[rg][kb].x, bf.x, acc[rg][j], 0, 0, 0);
          acc[rg][j] = __builtin_amdgcn_mfma_f32_16x16x32_fp8_fp8(
              af[rg][kb].y, bf.y, acc[rg][j], 0, 0, 0);
        }
      }
    }
  }

  // per-row max over all 128 cols: wave-local (rows are wave-exclusive)
#pragma unroll
  for (int rg = 0; rg < 2; ++rg) {
#pragma unroll
    for (int r = 0; r < 4; ++r) {
      float v = acc[rg][0][r];
#pragma unroll
      for (int j = 1; j < 8; ++j) v = fmaxf(v, acc[rg][j][r]);
#pragma unroll
      for (int off = 1; off < 16; off <<= 1) v = fmaxf(v, __shfl_xor(v, off));
      if (lcol == 0)
        wsmx[(size_t)blockIdx.y * 8192 + m0 + w * 32 + rg * 16 + quad * 4 + r] = v;
    }
  }
}

// ---------------------------------------------------------------------------
// softmax_xw: logit[m] = scale * mean_img( max over img's 8 col-tiles ); softmax per image
__global__ __launch_bounds__(1024) void softmax_xw(const float* __restrict__ wsmx,
                                                   float* __restrict__ xw) {
  const int b = blockIdx.x, p = threadIdx.x;
  const int m = b * 1024 + p;
  float s = 0.f;
#pragma unroll
  for (int img = 0; img < 8; ++img) {
    float mx = -1e30f;
#pragma unroll
    for (int t = 0; t < 8; ++t) mx = fmaxf(mx, wsmx[(size_t)(img * 8 + t) * 8192 + m]);
    s += mx;
  }
  const float logit = s * 0.005524271728019903f;  // (1/8) * (1/sqrt(512))
  __shared__ float red[16];
  float v = logit;
#pragma unroll
  for (int off = 32; off >= 1; off >>= 1) v = fmaxf(v, __shfl_xor(v, off));
  if ((p & 63) == 0) red[p >> 6] = v;
  __syncthreads();
  float bmax = red[0];
#pragma unroll
  for (int t = 1; t < 16; ++t) bmax = fmaxf(bmax, red[t]);
  const float e = expf(logit - bmax);
  float sv = e;
#pragma unroll
  for (int off = 32; off >= 1; off >>= 1) sv += __shfl_xor(sv, off);
  __syncthreads();
  if ((p & 63) == 0) red[p >> 6] = sv;
  __syncthreads();
  float bsum = 0.f;
#pragma unroll
  for (int t = 0; t < 16; ++t) bsum += red[t];
  xw[m] = e / bsum;
}

// ---------------------------------------------------------------------------
// epilogue_out: out[b][co][p] = z[b*1024+p][co] * xw[b*1024+p] + b6[co]
// z in bf16. grid (16 p-tiles, 8 c-tiles, 8 b), block 256.
__global__ __launch_bounds__(256) void epilogue_out(const short* __restrict__ z,
                                                    const float* __restrict__ xw,
                                                    const float* __restrict__ b6,
                                                    float* __restrict__ out) {
  const int p0 = blockIdx.x * 64, c0 = blockIdx.y * 64, b = blockIdx.z;
  __shared__ float t[64][65];  // t[co][p]
  const int u = threadIdx.x;
  {
    const int c4 = u & 15, pr = u >> 4;
    for (int pp = 0; pp < 4; ++pp) {
      const int p = pp * 16 + pr;
      const ushort4 v = *(const ushort4*)&z[((size_t)(b * 1024 + p0 + p)) * 512 + c0 + c4 * 4];
      t[c4 * 4 + 0][p] = bf2f(v.x);
      t[c4 * 4 + 1][p] = bf2f(v.y);
      t[c4 * 4 + 2][p] = bf2f(v.z);
      t[c4 * 4 + 3][p] = bf2f(v.w);
    }
  }
  __syncthreads();
  {
    const int p4 = u & 15, cr = u >> 4;
    const float4 wv = *(const float4*)&xw[b * 1024 + p0 + p4 * 4];
    for (int cc = 0; cc < 4; ++cc) {
      const int co = cc * 16 + cr;
      const float bias = b6[c0 + co];
      float4 o;
      o.x = t[co][p4 * 4 + 0] * wv.x + bias;
      o.y = t[co][p4 * 4 + 1] * wv.y + bias;
      o.z = t[co][p4 * 4 + 2] * wv.z + bias;
      o.w = t[co][p4 * 4 + 3] * wv.w + bias;
      *(float4*)&out[((size_t)(b * 512 + c0 + co)) * 1024 + p0 + p4 * 4] = o;
    }
  }
}

// ---------------------------------------------------------------------------
extern "C" void kernel_launch(void* const* d_in, const int* in_sizes, int n_in,
                              void* d_out, int out_size, void* d_ws, size_t ws_size,
                              hipStream_t stream) {
  const float* x  = (const float*)d_in[0];
  const float* Wq = (const float*)d_in[1];
  const float* bq = (const float*)d_in[2];
  const float* Wk = (const float*)d_in[3];
  const float* bk = (const float*)d_in[4];
  const float* W6 = (const float*)d_in[5];
  const float* b6 = (const float*)d_in[6];
  float* out = (float*)d_out;

  char* ws = (char*)d_ws;
  short* xt          = (short*)(ws + 0);               //  8 MB  bf16 [8192][512]
  short* wcat        = (short*)(ws + 8388608);         //  1.5MB bf16 [1536][512]
  unsigned char* qk8 = (unsigned char*)(ws + 10485760);//  8 MB  fp8  [8192][1024]
  short* z           = (short*)(ws + 18874368);        //  8 MB  bf16 [8192][512]
  float* wsmx        = (float*)(ws + 27262976);        //  2 MB  fp32 [64][8192]
  float* xw          = (float*)(ws + 29360128);        // 32 KB  fp32 [8192]

  prep<<<1792, 256, 0, stream>>>(x, Wq, Wk, W6, xt, wcat);
  gemm_qkz<<<dim3(64, 12), 256, 0, stream>>>(xt, wcat, bq, bk, qk8, z);
  gemm_scores<<<dim3(64, 64), 256, 0, stream>>>(qk8, wsmx);
  softmax_xw<<<8, 1024, 0, stream>>>(wsmx, xw);
  epilogue_out<<<dim3(16, 8, 8), 256, 0, stream>>>(z, xw, b6, out);
}

// Round 9
// 181.808 us; speedup vs baseline: 1.8561x; 1.0546x over previous
//
#include <hip/hip_runtime.h>

// B=8, C=512, H=W=32, HW=1024, M=8192. scale = 1/sqrt(512).
// prep (x transpose->bf16, W pack->bf16)
// gemm_qkz (bf16 MFMA, R5-hybrid: A per-lane global, B staged LDS frag-ordered,
//           8 barriers; q|k -> fp8 qk8 via v_cvt_pk_fp8_f32 (+bias), z -> bf16)
// gemm_scores (fp8 MFMA, R5 hybrid, 4 barriers) [R8 verbatim, 73 us]
// softmax_xw ; epilogue_out (out = z*xw + b6, LDS transpose)

typedef __attribute__((ext_vector_type(8))) short bf16x8;
typedef __attribute__((ext_vector_type(4))) float f32x4;
typedef __attribute__((ext_vector_type(2))) long long i64x2;

__device__ __forceinline__ unsigned short f2bf(float f) {
  unsigned u = __builtin_bit_cast(unsigned, f);
  u += 0x7FFFu + ((u >> 16) & 1u);
  return (unsigned short)(u >> 16);
}

__device__ __forceinline__ float bf2f(unsigned short b) {
  return __builtin_bit_cast(float, (unsigned)b << 16);
}

__device__ __forceinline__ void gload_lds16(const void* g, void* l) {
  __builtin_amdgcn_global_load_lds(
      (const __attribute__((address_space(1))) unsigned int*)g,
      (__attribute__((address_space(3))) unsigned int*)l, 16, 0, 0);
}

// ---------------------------------------------------------------------------
// prep: blocks [0,1024): transpose x [b][c][p] -> xt [b*1024+p][c] bf16
//       blocks [1024,1792): pack Wq|Wk|W6 -> wcat bf16 [1536][512]
__global__ __launch_bounds__(256) void prep(const float* __restrict__ x,
                                            const float* __restrict__ Wq,
                                            const float* __restrict__ Wk,
                                            const float* __restrict__ W6,
                                            short* __restrict__ xt,
                                            short* __restrict__ wcat) {
  const int bid = blockIdx.x, u = threadIdx.x;
  if (bid < 1024) {
    const int p0 = (bid & 15) * 64, c0 = ((bid >> 4) & 7) * 64, b = bid >> 7;
    __shared__ float t[64][65];
    {
      const int p4 = u & 15, cr = u >> 4;
      for (int cc = 0; cc < 4; ++cc) {
        const int c = cc * 16 + cr;
        const float4 v = *(const float4*)&x[((size_t)(b * 512 + c0 + c)) * 1024 + p0 + p4 * 4];
        t[p4 * 4 + 0][c] = v.x; t[p4 * 4 + 1][c] = v.y;
        t[p4 * 4 + 2][c] = v.z; t[p4 * 4 + 3][c] = v.w;
      }
    }
    __syncthreads();
    {
      const int c4 = u & 15, pr = u >> 4;
      for (int pp = 0; pp < 4; ++pp) {
        const int p = pp * 16 + pr;
        ushort4 o;
        o.x = f2bf(t[p][c4 * 4 + 0]); o.y = f2bf(t[p][c4 * 4 + 1]);
        o.z = f2bf(t[p][c4 * 4 + 2]); o.w = f2bf(t[p][c4 * 4 + 3]);
        *(ushort4*)&xt[((size_t)(b * 1024 + p0 + p)) * 512 + c0 + c4 * 4] = o;
      }
    }
  } else {
    const int i = (bid - 1024) * 256 + u;
    const int idx = i * 4;
    const float* src = (idx < 262144) ? Wq : (idx < 524288) ? Wk : W6;
    const float4 v = *(const float4*)&src[idx & 262143];
    ushort4 o;
    o.x = f2bf(v.x); o.y = f2bf(v.y); o.z = f2bf(v.z); o.w = f2bf(v.w);
    *(ushort4*)&wcat[idx] = o;
  }
}

// ---------------------------------------------------------------------------
// gemm_qkz: C[8192][1536] = xt @ wcat^T, R5-hybrid structure.
// Block 128x128, grid (64,12); wave w owns rows [m0+w*32,+32): acc[2][8].
// A streamed per-lane from global: bf16 frag = 16 B at row*1024B + k-step*64B
// + quad*16B (row pitch 512 shorts = 1024 B, same addressing as fp8 scores).
// B staged in LDS in 4 K-chunks of 128 elems: per (j,kb) 1 KB lane-ordered
// (lane*8 shorts) -> frag read = bf16x8 at lane*8, conflict-free. 32 KB LDS.
// Cols 0..1023 -> qk8 fp8 (+bias, HW v_cvt_pk_fp8_f32); 1024..1535 -> z bf16.
__global__ __launch_bounds__(256) void gemm_qkz(const short* __restrict__ xt,
                                                const short* __restrict__ wcat,
                                                const float* __restrict__ bq,
                                                const float* __restrict__ bk,
                                                unsigned char* __restrict__ qk8,
                                                short* __restrict__ z) {
  __shared__ short lds_b[16384];  // 32 KB: 8 j-groups x 4 kb x 512 shorts
  const int tid = threadIdx.x, w = tid >> 6, lane = tid & 63;
  const int quad = lane >> 4, lcol = lane & 15;
  const int srow = lane & 15, skq = lane >> 4;  // staging: row in j-group, 8-elem quad
  const int m0 = blockIdx.x * 128, n0 = blockIdx.y * 128;

  f32x4 acc[2][8];
#pragma unroll
  for (int rg = 0; rg < 2; ++rg)
#pragma unroll
    for (int j = 0; j < 8; ++j)
#pragma unroll
      for (int r = 0; r < 4; ++r) acc[rg][j][r] = 0.f;

  // A: per-lane; row = m0 + w*32 + rg*16 + srow, k-elems kh*128 + kb*32 + skq*8
  const short* Abase = xt + (size_t)(m0 + w * 32 + srow) * 512 + skq * 8;
  // B: staging source; row = n0 + j*16 + srow
  const short* Bbase = wcat + (size_t)(n0 + srow) * 512 + skq * 8;

#pragma unroll
  for (int kh = 0; kh < 4; ++kh) {
    const int ke = kh * 128;  // k-elem base of this chunk
    __syncthreads();  // previous chunk fully consumed before overwrite
#pragma unroll
    for (int jj = 0; jj < 2; ++jj) {
      const int j = w * 2 + jj;
#pragma unroll
      for (int kb = 0; kb < 4; ++kb)
        gload_lds16(Bbase + (size_t)(j * 16) * 512 + ke + kb * 32,
                    lds_b + j * 2048 + kb * 512);
    }
    // prefetch this chunk's A (2 rg x 4 kb x 16 B) while glds are in flight
    bf16x8 af[2][4];
#pragma unroll
    for (int rg = 0; rg < 2; ++rg)
#pragma unroll
      for (int kb = 0; kb < 4; ++kb)
        af[rg][kb] = *(const bf16x8*)(Abase + (size_t)rg * 16 * 512 + ke + kb * 32);
    __syncthreads();  // B chunk ready
#pragma unroll
    for (int kb = 0; kb < 4; ++kb) {
#pragma unroll
      for (int j = 0; j < 8; ++j) {
        const bf16x8 bf = *(const bf16x8*)&lds_b[j * 2048 + kb * 512 + lane * 8];
#pragma unroll
        for (int rg = 0; rg < 2; ++rg)
          acc[rg][j] = __builtin_amdgcn_mfma_f32_16x16x32_bf16(af[rg][kb], bf, acc[rg][j], 0, 0, 0);
      }
    }
  }

  const int region = (int)blockIdx.y >> 2;  // 0=q, 1=k, 2=z (uniform per block)
  if (region < 2) {
    const float* bias = region ? bk : bq;
#pragma unroll
    for (int rg = 0; rg < 2; ++rg) {
      const int row = m0 + w * 32 + rg * 16 + quad * 4;
#pragma unroll
      for (int j = 0; j < 8; ++j) {
        const int col = n0 + j * 16 + lcol;
        const float bv = bias[col & 511];
        const int p01 = __builtin_amdgcn_cvt_pk_fp8_f32(
            acc[rg][j][0] + bv, acc[rg][j][1] + bv, 0, false);
        const int p23 = __builtin_amdgcn_cvt_pk_fp8_f32(
            acc[rg][j][2] + bv, acc[rg][j][3] + bv, 0, false);
        qk8[(size_t)(row + 0) * 1024 + col] = (unsigned char)(p01 & 0xFF);
        qk8[(size_t)(row + 1) * 1024 + col] = (unsigned char)((p01 >> 8) & 0xFF);
        qk8[(size_t)(row + 2) * 1024 + col] = (unsigned char)(p23 & 0xFF);
        qk8[(size_t)(row + 3) * 1024 + col] = (unsigned char)((p23 >> 8) & 0xFF);
      }
    }
  } else {
#pragma unroll
    for (int rg = 0; rg < 2; ++rg) {
      const int row = m0 + w * 32 + rg * 16 + quad * 4;
#pragma unroll
      for (int j = 0; j < 8; ++j) {
        const int col = n0 - 1024 + j * 16 + lcol;
#pragma unroll
        for (int r = 0; r < 4; ++r)
          z[(size_t)(row + r) * 512 + col] = (short)f2bf(acc[rg][j][r]);
      }
    }
  }
}

// ---------------------------------------------------------------------------
// gemm_scores: q @ k^T (fp8 MFMA), R5 hybrid structure [73 us measured].
// Block tile 128x128; wave w owns rows [m0+w*32, +32) x all 128 cols: acc[2][8].
// A streamed per-lane straight from global; B staged in LDS in 2 half-K
// (256 B) stages, frag-ordered. 4 __syncthreads per block.
__global__ __launch_bounds__(256) void gemm_scores(const unsigned char* __restrict__ qk8,
                                                   float* __restrict__ wsmx) {
  __shared__ unsigned char lds_b[32768];
  const int tid = threadIdx.x, w = tid >> 6, lane = tid & 63;
  const int quad = lane >> 4, lcol = lane & 15;
  const int srow = lane & 15, skb = (lane >> 4) * 16;
  const int m0 = blockIdx.x * 128, n0 = blockIdx.y * 128;

  f32x4 acc[2][8];
#pragma unroll
  for (int rg = 0; rg < 2; ++rg)
#pragma unroll
    for (int j = 0; j < 8; ++j)
#pragma unroll
      for (int r = 0; r < 4; ++r) acc[rg][j][r] = 0.f;

  const unsigned char* Abase = qk8 + (size_t)(m0 + w * 32 + srow) * 1024 + skb;
  const unsigned char* Bbase = qk8 + (size_t)(n0 + srow) * 1024 + 512 + skb;

#pragma unroll
  for (int kh = 0; kh < 2; ++kh) {
    __syncthreads();  // previous half fully consumed before overwrite
#pragma unroll
    for (int jj = 0; jj < 2; ++jj) {
      const int j = w * 2 + jj;
#pragma unroll
      for (int kb = 0; kb < 4; ++kb)
        gload_lds16(Bbase + (size_t)(j * 16) * 1024 + kh * 256 + kb * 64,
                    lds_b + j * 4096 + kb * 1024);
    }
    // prefetch this half's A (8 x 16B) while glds are in flight
    i64x2 af[2][4];
#pragma unroll
    for (int rg = 0; rg < 2; ++rg)
#pragma unroll
      for (int kb = 0; kb < 4; ++kb)
        af[rg][kb] = *(const i64x2*)(Abase + (size_t)rg * 16384 + kh * 256 + kb * 64);
    __syncthreads();  // B half ready
#pragma unroll
    for (int kb = 0; kb < 4; ++kb) {
#pragma unroll
      for (int j = 0; j < 8; ++j) {
        const i64x2 bf = *(const i64x2*)&lds_b[j * 4096 + kb * 1024 + lane * 16];
#pragma unroll
        for (int rg = 0; rg < 2; ++rg) {
          acc[rg][j] = __builtin_amdgcn_mfma_f32_16x16x32_fp8_fp8(
              af[rg][kb].x, bf.x, acc[rg][j], 0, 0, 0);
          acc[rg][j] = __builtin_amdgcn_mfma_f32_16x16x32_fp8_fp8(
              af[rg][kb].y, bf.y, acc[rg][j], 0, 0, 0);
        }
      }
    }
  }

  // per-row max over all 128 cols: wave-local (rows are wave-exclusive)
#pragma unroll
  for (int rg = 0; rg < 2; ++rg) {
#pragma unroll
    for (int r = 0; r < 4; ++r) {
      float v = acc[rg][0][r];
#pragma unroll
      for (int j = 1; j < 8; ++j) v = fmaxf(v, acc[rg][j][r]);
#pragma unroll
      for (int off = 1; off < 16; off <<= 1) v = fmaxf(v, __shfl_xor(v, off));
      if (lcol == 0)
        wsmx[(size_t)blockIdx.y * 8192 + m0 + w * 32 + rg * 16 + quad * 4 + r] = v;
    }
  }
}

// ---------------------------------------------------------------------------
// softmax_xw: logit[m] = scale * mean_img( max over img's 8 col-tiles ); softmax per image
__global__ __launch_bounds__(1024) void softmax_xw(const float* __restrict__ wsmx,
                                                   float* __restrict__ xw) {
  const int b = blockIdx.x, p = threadIdx.x;
  const int m = b * 1024 + p;
  float s = 0.f;
#pragma unroll
  for (int img = 0; img < 8; ++img) {
    float mx = -1e30f;
#pragma unroll
    for (int t = 0; t < 8; ++t) mx = fmaxf(mx, wsmx[(size_t)(img * 8 + t) * 8192 + m]);
    s += mx;
  }
  const float logit = s * 0.005524271728019903f;  // (1/8) * (1/sqrt(512))
  __shared__ float red[16];
  float v = logit;
#pragma unroll
  for (int off = 32; off >= 1; off >>= 1) v = fmaxf(v, __shfl_xor(v, off));
  if ((p & 63) == 0) red[p >> 6] = v;
  __syncthreads();
  float bmax = red[0];
#pragma unroll
  for (int t = 1; t < 16; ++t) bmax = fmaxf(bmax, red[t]);
  const float e = expf(logit - bmax);
  float sv = e;
#pragma unroll
  for (int off = 32; off >= 1; off >>= 1) sv += __shfl_xor(sv, off);
  __syncthreads();
  if ((p & 63) == 0) red[p >> 6] = sv;
  __syncthreads();
  float bsum = 0.f;
#pragma unroll
  for (int t = 0; t < 16; ++t) bsum += red[t];
  xw[m] = e / bsum;
}

// ---------------------------------------------------------------------------
// epilogue_out: out[b][co][p] = z[b*1024+p][co] * xw[b*1024+p] + b6[co]
// z in bf16. grid (16 p-tiles, 8 c-tiles, 8 b), block 256.
__global__ __launch_bounds__(256) void epilogue_out(const short* __restrict__ z,
                                                    const float* __restrict__ xw,
                                                    const float* __restrict__ b6,
                                                    float* __restrict__ out) {
  const int p0 = blockIdx.x * 64, c0 = blockIdx.y * 64, b = blockIdx.z;
  __shared__ float t[64][65];  // t[co][p]
  const int u = threadIdx.x;
  {
    const int c4 = u & 15, pr = u >> 4;
    for (int pp = 0; pp < 4; ++pp) {
      const int p = pp * 16 + pr;
      const ushort4 v = *(const ushort4*)&z[((size_t)(b * 1024 + p0 + p)) * 512 + c0 + c4 * 4];
      t[c4 * 4 + 0][p] = bf2f(v.x);
      t[c4 * 4 + 1][p] = bf2f(v.y);
      t[c4 * 4 + 2][p] = bf2f(v.z);
      t[c4 * 4 + 3][p] = bf2f(v.w);
    }
  }
  __syncthreads();
  {
    const int p4 = u & 15, cr = u >> 4;
    const float4 wv = *(const float4*)&xw[b * 1024 + p0 + p4 * 4];
    for (int cc = 0; cc < 4; ++cc) {
      const int co = cc * 16 + cr;
      const float bias = b6[c0 + co];
      float4 o;
      o.x = t[co][p4 * 4 + 0] * wv.x + bias;
      o.y = t[co][p4 * 4 + 1] * wv.y + bias;
      o.z = t[co][p4 * 4 + 2] * wv.z + bias;
      o.w = t[co][p4 * 4 + 3] * wv.w + bias;
      *(float4*)&out[((size_t)(b * 512 + c0 + co)) * 1024 + p0 + p4 * 4] = o;
    }
  }
}

// ---------------------------------------------------------------------------
extern "C" void kernel_launch(void* const* d_in, const int* in_sizes, int n_in,
                              void* d_out, int out_size, void* d_ws, size_t ws_size,
                              hipStream_t stream) {
  const float* x  = (const float*)d_in[0];
  const float* Wq = (const float*)d_in[1];
  const float* bq = (const float*)d_in[2];
  const float* Wk = (const float*)d_in[3];
  const float* bk = (const float*)d_in[4];
  const float* W6 = (const float*)d_in[5];
  const float* b6 = (const float*)d_in[6];
  float* out = (float*)d_out;

  char* ws = (char*)d_ws;
  short* xt          = (short*)(ws + 0);               //  8 MB  bf16 [8192][512]
  short* wcat        = (short*)(ws + 8388608);         //  1.5MB bf16 [1536][512]
  unsigned char* qk8 = (unsigned char*)(ws + 10485760);//  8 MB  fp8  [8192][1024]
  short* z           = (short*)(ws + 18874368);        //  8 MB  bf16 [8192][512]
  float* wsmx        = (float*)(ws + 27262976);        //  2 MB  fp32 [64][8192]
  float* xw          = (float*)(ws + 29360128);        // 32 KB  fp32 [8192]

  prep<<<1792, 256, 0, stream>>>(x, Wq, Wk, W6, xt, wcat);
  gemm_qkz<<<dim3(64, 12), 256, 0, stream>>>(xt, wcat, bq, bk, qk8, z);
  gemm_scores<<<dim3(64, 64), 256, 0, stream>>>(qk8, wsmx);
  softmax_xw<<<8, 1024, 0, stream>>>(wsmx, xw);
  epilogue_out<<<dim3(16, 8, 8), 256, 0, stream>>>(z, xw, b6, out);
}